// Round 16
// baseline (68.909 us; speedup 1.0000x reference)
//
#include <hip/hip_runtime.h>
#include <hip/hip_bf16.h>

#define SLEN 4096
#define NH   16
#define DH   64
#define WW   256
#define GMAX 64

typedef unsigned short u16;
typedef unsigned int   u32;
typedef unsigned long long u64;
typedef __attribute__((ext_vector_type(8))) short bf16x8;
typedef __attribute__((ext_vector_type(4))) float f32x4;

#define MFMA16(a,b,c) __builtin_amdgcn_mfma_f32_16x16x32_bf16((a),(b),(c),0,0,0)

static __device__ __forceinline__ int imin(int a, int b) { return a < b ? a : b; }
static __device__ __forceinline__ int imax(int a, int b) { return a > b ? a : b; }

__device__ __forceinline__ u32 cvtpk(float lo, float hi) {
  u32 r;
  asm("v_cvt_pk_bf16_f32 %0, %1, %2" : "=v"(r) : "v"(lo), "v"(hi));
  return r;
}
__device__ __forceinline__ u16 f2bf(float x) {
  u32 u = __float_as_uint(x);
  u32 r = (u + 0x7fffu + ((u >> 16) & 1u)) >> 16;
  return (u16)r;
}
// gather bit0 of each byte of mw into bits [3:0]
__device__ __forceinline__ u32 bitg(u32 mw) {
  return (((mw & 0x01010101u) * 0x01020408u) >> 24) & 0xFu;
}

__device__ __forceinline__ void gload16(const u16* src, u16* lds_base) {
  __builtin_amdgcn_global_load_lds((const __attribute__((address_space(1))) u32*)src,
                                   (__attribute__((address_space(3))) u32*)lds_base,
                                   16, 0, 0);
}

// ---------------- prep1: k-conv + V transpose (tiled, σ) + meta + fused gather ----------
__global__ __launch_bounds__(256) void lf_prep1(
    const float* __restrict__ qF, const float* __restrict__ k, const float* __restrict__ v,
    const int* __restrict__ gmask, const int* __restrict__ pmask, const int* __restrict__ nGp,
    u16* __restrict__ kB, u16* __restrict__ vtB,
    int* __restrict__ gpos, unsigned char* __restrict__ gmsk,
    unsigned char* __restrict__ msk, unsigned char* __restrict__ cleanmap,
    u16* __restrict__ gq, u16* __restrict__ gk, u16* __restrict__ gvt, float qscale) {
  const int bid = blockIdx.x;
  const int tid = threadIdx.x;
  if (bid < 2048) {
    int i = (bid * 256 + tid) * 8;
    float4 v0 = *(const float4*)(k + i);
    float4 v1 = *(const float4*)(k + i + 4);
    uint4 w;
    w.x = cvtpk(v0.x, v0.y);
    w.y = cvtpk(v0.z, v0.w);
    w.z = cvtpk(v1.x, v1.y);
    w.w = cvtpk(v1.z, v1.w);
    *(uint4*)(kB + i) = w;
    return;
  }
  if (bid < 3072) {
    __shared__ float t[64][65];
    int b = bid - 2048;
    int h = b >> 6, s0 = (b & 63) << 6;
    int tile = h * 64 + (b & 63);
    int r = tid >> 2, c0 = (tid & 3) << 4;
    const float* src = v + ((size_t)h * SLEN + s0 + r) * DH + c0;
#pragma unroll
    for (int j = 0; j < 16; j += 4) {
      float4 a = *(const float4*)(src + j);
      t[r][c0 + j]     = a.x;
      t[r][c0 + j + 1] = a.y;
      t[r][c0 + j + 2] = a.z;
      t[r][c0 + j + 3] = a.w;
    }
    __syncthreads();
    int d = tid >> 2, j0 = (tid & 3) << 4;
    int grp  = j0 & 32;
    int half = (j0 & 16) ? 4 : 0;
    u16* dst = vtB + ((size_t)tile * 64 + d) * 64 + grp;
#pragma unroll
    for (int q4 = 0; q4 < 4; ++q4) {
      uint2 val;
      val.x = cvtpk(t[j0 + 4 * q4 + 0][d], t[j0 + 4 * q4 + 1][d]);
      val.y = cvtpk(t[j0 + 4 * q4 + 2][d], t[j0 + 4 * q4 + 3][d]);
      *(uint2*)(dst + 8 * q4 + half) = val;
    }
    return;
  }
  if (bid == 3072) {
    const int G = imin(nGp[0], GMAX);
    for (int s = tid; s < SLEN; s += 256) {
      unsigned char b = (unsigned char)((pmask[s] ? 1 : 0) | (gmask[s] ? 2 : 0));
      msk[s] = b;
    }
    for (int s = SLEN + tid; s < SLEN + 64; s += 256) msk[s] = 0;
    __syncthreads();
    if (tid < 64) {
      int lane = tid;
      if (lane < GMAX) gmsk[lane] = 0;
      int cnt = 0;
      for (int c = 0; c < SLEN / 64 && cnt < G; ++c) {
        int s = c * 64 + lane;
        bool isg = gmask[s] != 0;
        u64 b = __ballot(isg);
        int rank = cnt + (int)__popcll(b & ((1ull << lane) - 1ull));
        if (isg && rank < G) gpos[rank] = s;
        cnt += (int)__popcll(b);
      }
      if (cnt < G) {
        int fill = cnt;
        for (int c = 0; c < SLEN / 64 && fill < G; ++c) {
          int s = c * 64 + lane;
          bool non = gmask[s] == 0;
          u64 b = __ballot(non);
          int rank = fill + (int)__popcll(b & ((1ull << lane) - 1ull));
          if (non && rank < G) gpos[rank] = s;
          fill += (int)__popcll(b);
        }
      }
    }
    __syncthreads();
    if (tid < 64) {
      if (tid < G) {
        int p = gpos[tid];
        gmsk[tid] = (unsigned char)(pmask[p] ? 1 : 0);
        msk[p] = (unsigned char)(msk[p] | 4);
      }
    } else if (tid >= 128) {
      int c = tid - 128;
      if (c < SLEN / 32) {
        unsigned char ok1 = 1, ok2 = 1;
        for (int kk = 0; kk < 32; ++kk) {
          unsigned char b = msk[c * 32 + kk];
          ok1 &= (unsigned char)(((b & 3) == 1) ? 1 : 0);
          ok2 &= (unsigned char)(b & 1);
        }
        cleanmap[c] = (unsigned char)(ok1 | (ok2 << 1));
      }
    }
    return;
  }
  // ---- gather blocks (3073..3328): rebuild gpos locally, gather from RAW f32 ----
  __shared__ int sGpos[GMAX];
  const int G = imin(nGp[0], GMAX);
  if (tid < 64) {
    int lane = tid;
    int cnt = 0;
    for (int c = 0; c < SLEN / 64 && cnt < G; ++c) {
      int s = c * 64 + lane;
      bool isg = gmask[s] != 0;
      u64 b = __ballot(isg);
      int rank = cnt + (int)__popcll(b & ((1ull << lane) - 1ull));
      if (isg && rank < G) sGpos[rank] = s;
      cnt += (int)__popcll(b);
    }
    if (cnt < G) {
      int fill = cnt;
      for (int c = 0; c < SLEN / 64 && fill < G; ++c) {
        int s = c * 64 + lane;
        bool non = gmask[s] == 0;
        u64 b = __ballot(non);
        int rank = fill + (int)__popcll(b & ((1ull << lane) - 1ull));
        if (non && rank < G) sGpos[rank] = s;
        fill += (int)__popcll(b);
      }
    }
  }
  __syncthreads();
  int idx = (bid - 3073) * 256 + tid;
  int h = idx >> 12, m = (idx >> 6) & 63, d = idx & 63;
  size_t oq = ((size_t)h * GMAX + m) * DH + d;
  int r = m & 31;
  int pos = ((r & 12) << 1) + ((r & 16) >> 2) + (r & 3);
  size_t ot = ((size_t)h * DH + d) * GMAX + (m & 32) + pos;
  if (m < G) {
    int p = sGpos[m];
    gq[oq]  = f2bf(qF[((size_t)h * SLEN + p) * DH + d] * qscale);
    gk[oq]  = f2bf(k[((size_t)h * SLEN + p) * DH + d]);
    gvt[ot] = f2bf(v[((size_t)h * SLEN + p) * DH + d]);
  } else {
    gq[oq] = 0; gk[oq] = 0; gvt[ot] = 0;
  }
}

// ---------------- unified attention: R15 structure, masks in regs, LDS = exactly 32KB ------
// 1152 blocks x 256 thr, 5 blocks/CU (all co-resident). wg XCD-swizzled; wg%9==0 -> global.
// Local: fixed 9-tile window t0=clamp(qblk-4,0,55) + gtile -> 10 unrolled phases.
// Global: 8 unrolled phases. Mask bits live in mreg[]/gmreg (static-indexed).
__global__ __launch_bounds__(256, 5) void lf_attn(
    const float* __restrict__ qF, const u16* __restrict__ kB, const u16* __restrict__ vtB,
    const u16* __restrict__ gkB, const u16* __restrict__ gqB, const u16* __restrict__ gvtB,
    const unsigned char* __restrict__ gmskA, const unsigned char* __restrict__ mskA,
    const unsigned char* __restrict__ cleanA, const int* __restrict__ nGp,
    float* __restrict__ out, float* __restrict__ pAcc, float* __restrict__ pL, float qscale) {
  __shared__ __align__(16) u16 sK[2][4096];
  __shared__ __align__(16) u16 sV[2][4096];    // total 32768 B exactly

  const int tid  = threadIdx.x;
  const int wv   = tid >> 6;
  const int lane = tid & 63;
  const int ql   = lane & 15;
  const int g    = lane >> 4;
  const float NEGV = -1e30f;
  const float MEXP = 24.0f;

  const int wg = ((int)blockIdx.x & 7) * 144 + ((int)blockIdx.x >> 3);
  const bool glob = (wg % 9) == 0;

  int off[4][2];
#pragma unroll
  for (int t = 0; t < 4; ++t)
#pragma unroll
    for (int c = 0; c < 2; ++c) {
      int row = 16 * t + ql;
      off[t][c] = (row * 8 + ((c * 4 + g) ^ (row & 7))) * 8;
    }

  f32x4 acc[4];
#pragma unroll
  for (int i = 0; i < 4; ++i) acc[i] = (f32x4){0.f, 0.f, 0.f, 0.f};
  f32x4 lsv = (f32x4){0.f, 0.f, 0.f, 0.f};
  bf16x8 qf0, qf1;

  // softmax->pack->PV tail shared by all paths
  auto TAIL = [&](const f32x4 (&pv)[4], const u16* sv) {
    lsv += pv[0] + pv[1] + pv[2] + pv[3];
#pragma unroll
    for (int s2 = 0; s2 < 2; ++s2) {
      union { u32 w[4]; bf16x8 v8; } u;
      u.w[0] = cvtpk(pv[2 * s2][0], pv[2 * s2][1]);
      u.w[1] = cvtpk(pv[2 * s2][2], pv[2 * s2][3]);
      u.w[2] = cvtpk(pv[2 * s2 + 1][0], pv[2 * s2 + 1][1]);
      u.w[3] = cvtpk(pv[2 * s2 + 1][2], pv[2 * s2 + 1][3]);
#pragma unroll
      for (int dt = 0; dt < 4; ++dt) {
        bf16x8 vf = *(const bf16x8*)(sv + off[dt][s2]);
        acc[dt] = MFMA16(vf, u.v8, acc[dt]);
      }
    }
  };
  auto QK = [&](const u16* sk, f32x4 (&sc)[4]) {
#pragma unroll
    for (int t = 0; t < 4; ++t) sc[t] = (f32x4){0.f, 0.f, 0.f, 0.f};
    __builtin_amdgcn_s_setprio(1);
#pragma unroll
    for (int t = 0; t < 4; ++t) {
      bf16x8 a0 = *(const bf16x8*)(sk + off[t][0]);
      bf16x8 a1 = *(const bf16x8*)(sk + off[t][1]);
      sc[t] = MFMA16(a0, qf0, sc[t]);
      sc[t] = MFMA16(a1, qf1, sc[t]);
    }
    __builtin_amdgcn_s_setprio(0);
  };

  if (!glob) {
    // ================= LOCAL =================
    int lid = wg - wg / 9 - 1;           // 0..1023
    const int h = lid >> 6;
    const int qblk = lid & 63;
    const int s0 = qblk << 6;
    const int s0w = s0 + 16 * wv;
    const int sq = s0w + ql;
    const int t0 = imin(imax(0, qblk - 4), 55);      // fixed 9-tile window
    const int lo_w = imax(t0, (s0w - WW) >> 6);
    const int hi_w = imin(t0 + 8, (s0w + 15 + WW) >> 6);

    const float* qr = qF + ((size_t)h * SLEN + sq) * DH;
    {
      float4 a0 = *(const float4*)(qr + 8 * g);
      float4 a1 = *(const float4*)(qr + 8 * g + 4);
      float4 b0 = *(const float4*)(qr + 32 + 8 * g);
      float4 b1 = *(const float4*)(qr + 32 + 8 * g + 4);
      union { u32 w[4]; bf16x8 v; } uq;
      uq.w[0] = cvtpk(a0.x * qscale, a0.y * qscale);
      uq.w[1] = cvtpk(a0.z * qscale, a0.w * qscale);
      uq.w[2] = cvtpk(a1.x * qscale, a1.y * qscale);
      uq.w[3] = cvtpk(a1.z * qscale, a1.w * qscale);
      qf0 = uq.v;
      uq.w[0] = cvtpk(b0.x * qscale, b0.y * qscale);
      uq.w[1] = cvtpk(b0.z * qscale, b0.w * qscale);
      uq.w[2] = cvtpk(b1.x * qscale, b1.y * qscale);
      uq.w[3] = cvtpk(b1.z * qscale, b1.w * qscale);
      qf1 = uq.v;
    }
    const u16* gks = gkB + (size_t)h * GMAX * DH;
    const u16* gvs = gvtB + (size_t)h * 4096;
    const u16* kbase = kB  + (size_t)h * 64 * 4096;
    const u16* vbase = vtB + (size_t)h * 64 * 4096;

    // clean bits + mask registers (static-indexed)
    unsigned char cbyte = 0;
    if (lane < 9)
      cbyte = (unsigned char)(cleanA[2 * (t0 + lane)] & cleanA[2 * (t0 + lane) + 1]);
    const u64 cbits = __ballot((cbyte & 1) != 0);
    u32 mreg[9], gmreg = 0;
#pragma unroll
    for (int idx = 0; idx < 9; ++idx) {
      u32 m = 0;
#pragma unroll
      for (int t = 0; t < 4; ++t) {
        u32 mw = *(const u32*)(mskA + (t0 + idx) * 64 + 16 * t + 4 * g);
        m |= (bitg(mw) << (4 * t)) | (bitg(mw >> 1) << (16 + 4 * t));
      }
      mreg[idx] = m;
    }
#pragma unroll
    for (int t = 0; t < 4; ++t) {
      u32 mw = *(const u32*)(gmskA + 16 * t + 4 * g);
      gmreg |= bitg(mw) << (4 * t);
    }

    auto stageL = [&](int p, int b) {
      const u16 *ks, *vs;
      if (p == 0) { ks = gks; vs = gvs; }
      else {
        int tv = t0 + p - 1;
        ks = kbase + (size_t)tv * 4096;
        vs = vbase + (size_t)tv * 4096;
      }
#pragma unroll
      for (int j = 0; j < 2; ++j) {
        int gran = (wv * 2 + j) * 64 + lane;
        int sg = gran ^ ((gran >> 3) & 7);
        gload16(ks + (size_t)sg * 8, &sK[b][(wv * 2 + j) * 512]);
        gload16(vs + (size_t)sg * 8, &sV[b][(wv * 2 + j) * 512]);
      }
    };

    stageL(0, 0);
#pragma unroll
    for (int p = 0; p < 10; ++p) {
      if (p < 9) {
        stageL(p + 1, (p + 1) & 1);
        asm volatile("s_waitcnt vmcnt(4)" ::: "memory");
      } else {
        asm volatile("s_waitcnt vmcnt(0)" ::: "memory");
      }
      __builtin_amdgcn_s_barrier();
      __builtin_amdgcn_sched_barrier(0);
      const u16* sk = &sK[p & 1][0];
      const u16* sv = &sV[p & 1][0];
      if (p == 0) {
        f32x4 sc[4];
        QK(sk, sc);
        f32x4 pv[4];
#pragma unroll
        for (int t = 0; t < 4; ++t)
#pragma unroll
          for (int i = 0; i < 4; ++i) {
            float s = ((gmreg >> (4 * t + i)) & 1) ? sc[t][i] : NEGV;
            pv[t][i] = __builtin_amdgcn_exp2f(s - MEXP);
          }
        TAIL(pv, sv);
      } else {
        const int idx = p - 1;
        const int tv = t0 + idx;
        const int kb = tv * 64;
        if (tv >= lo_w && tv <= hi_w) {
          f32x4 sc[4];
          QK(sk, sc);
          f32x4 pv[4];
          bool cl = (((cbits >> idx) & 1) != 0) &&
                    (kb >= s0w + 15 - WW) && (kb + 63 <= s0w + WW);
          if (cl) {
#pragma unroll
            for (int t = 0; t < 4; ++t)
#pragma unroll
              for (int i = 0; i < 4; ++i)
                pv[t][i] = __builtin_amdgcn_exp2f(sc[t][i] - MEXP);
          } else {
            u32 v2 = mreg[idx] & ~(mreg[idx] >> 16);   // pad & !glob per key
#pragma unroll
            for (int t = 0; t < 4; ++t)
#pragma unroll
              for (int i = 0; i < 4; ++i) {
                int kkey = kb + 16 * t + 4 * g + i;
                bool vok = ((v2 >> (4 * t + i)) & 1) && (kkey >= sq - WW) && (kkey <= sq + WW);
                float s = vok ? sc[t][i] : NEGV;
                pv[t][i] = __builtin_amdgcn_exp2f(s - MEXP);
              }
          }
          TAIL(pv, sv);
        }
      }
      __builtin_amdgcn_s_barrier();
    }

    float lsum = lsv[0] + lsv[1] + lsv[2] + lsv[3];
    lsum += __shfl_xor(lsum, 16);
    lsum += __shfl_xor(lsum, 32);
    float inv = 1.f / lsum;
    bool skip = (mskA[sq] & 4) != 0;
    if (!skip) {
      float* orow = out + ((size_t)h * SLEN + sq) * DH;
#pragma unroll
      for (int dt = 0; dt < 4; ++dt) {
        f32x4 o = acc[dt] * inv;
        *(f32x4*)(orow + dt * 16 + 4 * g) = o;
      }
    }
    return;
  }

  // ================= GLOBAL =================
  {
    int gb = wg / 9;                     // 0..127
    const int h = gb >> 3;
    const int splitIdx = gb & 7;
    const int qg = wv * 16 + ql;
    const int t0 = splitIdx * 8;
    const u16* qRow = gqB + ((size_t)h * GMAX + qg) * DH;
    qf0 = *(const bf16x8*)(qRow + 8 * g);
    qf1 = *(const bf16x8*)(qRow + 32 + 8 * g);
    const u16* kbase = kB  + (size_t)h * 64 * 4096;
    const u16* vbase = vtB + (size_t)h * 64 * 4096;

    unsigned char cbyte = 0;
    if (lane < 8)
      cbyte = (unsigned char)(cleanA[2 * (t0 + lane)] & cleanA[2 * (t0 + lane) + 1]);
    const u64 cbits = __ballot((cbyte & 2) != 0);
    u32 mreg[8];
#pragma unroll
    for (int idx = 0; idx < 8; ++idx) {
      u32 m = 0;
#pragma unroll
      for (int t = 0; t < 4; ++t) {
        u32 mw = *(const u32*)(mskA + (t0 + idx) * 64 + 16 * t + 4 * g);
        m |= bitg(mw) << (4 * t);        // pad bits only
      }
      mreg[idx] = m;
    }

    auto stageG = [&](int p, int b) {
      int tv = t0 + p;
      const u16* ks = kbase + (size_t)tv * 4096;
      const u16* vs = vbase + (size_t)tv * 4096;
#pragma unroll
      for (int j = 0; j < 2; ++j) {
        int gran = (wv * 2 + j) * 64 + lane;
        int sg = gran ^ ((gran >> 3) & 7);
        gload16(ks + (size_t)sg * 8, &sK[b][(wv * 2 + j) * 512]);
        gload16(vs + (size_t)sg * 8, &sV[b][(wv * 2 + j) * 512]);
      }
    };

    stageG(0, 0);
#pragma unroll
    for (int p = 0; p < 8; ++p) {
      if (p < 7) {
        stageG(p + 1, (p + 1) & 1);
        asm volatile("s_waitcnt vmcnt(4)" ::: "memory");
      } else {
        asm volatile("s_waitcnt vmcnt(0)" ::: "memory");
      }
      __builtin_amdgcn_s_barrier();
      __builtin_amdgcn_sched_barrier(0);
      const u16* sk = &sK[p & 1][0];
      const u16* sv = &sV[p & 1][0];
      f32x4 sc[4];
      QK(sk, sc);
      f32x4 pv[4];
      if ((cbits >> p) & 1) {
#pragma unroll
        for (int t = 0; t < 4; ++t)
#pragma unroll
          for (int i = 0; i < 4; ++i)
            pv[t][i] = __builtin_amdgcn_exp2f(sc[t][i] - MEXP);
      } else {
#pragma unroll
        for (int t = 0; t < 4; ++t)
#pragma unroll
          for (int i = 0; i < 4; ++i) {
            float s = ((mreg[p] >> (4 * t + i)) & 1) ? sc[t][i] : NEGV;
            pv[t][i] = __builtin_amdgcn_exp2f(s - MEXP);
          }
      }
      TAIL(pv, sv);
      __builtin_amdgcn_s_barrier();
    }

    float lsum = lsv[0] + lsv[1] + lsv[2] + lsv[3];
    lsum += __shfl_xor(lsum, 16);
    lsum += __shfl_xor(lsum, 32);
    float* pa = pAcc + ((size_t)(h * 8 + splitIdx) * 64 + qg) * 64;
#pragma unroll
    for (int dt = 0; dt < 4; ++dt)
      *(f32x4*)&pa[dt * 16 + 4 * g] = acc[dt];
    if (g == 0) pL[(h * 8 + splitIdx) * 64 + qg] = lsum;
  }
}

// ---------------- merge the 8 key-splits of global rows ----------------
__global__ void lf_gmerge(const float* __restrict__ pAcc, const float* __restrict__ pL,
                          const int* __restrict__ gpos, const int* __restrict__ nGp,
                          float* __restrict__ out) {
  const int G = imin(nGp[0], GMAX);
  int h = blockIdx.x;
  int tid = threadIdx.x;
#pragma unroll
  for (int it = 0; it < 4; ++it) {
    int v = tid + it * 256;
    int q = v >> 4, d4 = (v & 15) << 2;
    if (q >= G) continue;
    float L = 0.f;
    f32x4 a = (f32x4){0.f, 0.f, 0.f, 0.f};
#pragma unroll
    for (int s = 0; s < 8; ++s) {
      L += pL[(h * 8 + s) * 64 + q];
      a += *(const f32x4*)&pAcc[((size_t)(h * 8 + s) * 64 + q) * 64 + d4];
    }
    *(f32x4*)&out[((size_t)h * SLEN + gpos[q]) * DH + d4] = a * (1.f / L);
  }
}

// ---------------- launch ----------------
extern "C" void kernel_launch(void* const* d_in, const int* in_sizes, int n_in,
                              void* d_out, int out_size, void* d_ws, size_t ws_size,
                              hipStream_t stream) {
  const float* q = (const float*)d_in[0];
  const float* k = (const float*)d_in[1];
  const float* v = (const float*)d_in[2];
  const int* gmask = (const int*)d_in[3];
  const int* pmask = (const int*)d_in[4];
  const int* nGp = (const int*)d_in[5];
  float* out = (float*)d_out;
  char* ws = (char*)d_ws;

  constexpr size_t NEL = (size_t)NH * SLEN * DH;
  constexpr size_t OFF_KBF  = 0;
  constexpr size_t OFF_VTBF = OFF_KBF + NEL * 2;
  constexpr size_t OFF_GK   = OFF_VTBF + NEL * 2 + 256;
  constexpr size_t OFF_GQ   = OFF_GK + (size_t)NH * GMAX * DH * 2;
  constexpr size_t OFF_GVT  = OFF_GQ + (size_t)NH * GMAX * DH * 2;
  constexpr size_t OFF_GPOS = OFF_GVT + (size_t)NH * DH * GMAX * 2;
  constexpr size_t OFF_GMSK = OFF_GPOS + 256;
  constexpr size_t OFF_MSK  = OFF_GMSK + 64;
  constexpr size_t OFF_CLEAN = OFF_MSK + SLEN + 64;
  constexpr size_t OFF_PACC = OFF_CLEAN + 256;
  constexpr size_t OFF_PL   = OFF_PACC + (size_t)NH * 8 * 64 * 64 * 4;

  u16* kB  = (u16*)(ws + OFF_KBF);
  u16* vtB = (u16*)(ws + OFF_VTBF);
  u16* gk  = (u16*)(ws + OFF_GK);
  u16* gq  = (u16*)(ws + OFF_GQ);
  u16* gvt = (u16*)(ws + OFF_GVT);
  int* gpos = (int*)(ws + OFF_GPOS);
  unsigned char* gmsk = (unsigned char*)(ws + OFF_GMSK);
  unsigned char* msk  = (unsigned char*)(ws + OFF_MSK);
  unsigned char* clean = (unsigned char*)(ws + OFF_CLEAN);
  float* pAcc = (float*)(ws + OFF_PACC);
  float* pL   = (float*)(ws + OFF_PL);

  const float qscale = 0.125f * 1.4426950408889634f;  // 1/sqrt(64) * log2(e)

  lf_prep1<<<3329, 256, 0, stream>>>(q, k, v, gmask, pmask, nGp,
                                     kB, vtB, gpos, gmsk, msk, clean,
                                     gq, gk, gvt, qscale);
  lf_attn<<<1152, 256, 0, stream>>>(q, kB, vtB, gk, gq, gvt, gmsk, msk, clean,
                                    nGp, out, pAcc, pL, qscale);
  lf_gmerge<<<NH, 256, 0, stream>>>(pAcc, pL, gpos, nGp, out);
}

// Round 17
// 50.915 us; speedup vs baseline: 1.3534x; 1.3534x over previous
//
#include <hip/hip_runtime.h>
#include <hip/hip_bf16.h>

#define SLEN 4096
#define NH   16
#define DH   64
#define WW   256
#define GMAX 64

typedef unsigned short u16;
typedef unsigned int   u32;
typedef unsigned long long u64;
typedef __attribute__((ext_vector_type(8))) short bf16x8;
typedef __attribute__((ext_vector_type(4))) float f32x4;

#define MFMA16(a,b,c) __builtin_amdgcn_mfma_f32_16x16x32_bf16((a),(b),(c),0,0,0)

static __device__ __forceinline__ int imin(int a, int b) { return a < b ? a : b; }
static __device__ __forceinline__ int imax(int a, int b) { return a > b ? a : b; }

__device__ __forceinline__ u32 cvtpk(float lo, float hi) {
  u32 r;
  asm("v_cvt_pk_bf16_f32 %0, %1, %2" : "=v"(r) : "v"(lo), "v"(hi));
  return r;
}
__device__ __forceinline__ u16 f2bf(float x) {
  u32 u = __float_as_uint(x);
  u32 r = (u + 0x7fffu + ((u >> 16) & 1u)) >> 16;
  return (u16)r;
}

__device__ __forceinline__ void gload16(const u16* src, u16* lds_base) {
  __builtin_amdgcn_global_load_lds((const __attribute__((address_space(1))) u32*)src,
                                   (__attribute__((address_space(3))) u32*)lds_base,
                                   16, 0, 0);
}

// ---------------- prep1: k-conv + V transpose (tiled, σ) + meta + fused gather ----------
// grid: [0,2048) k-conv, [2048,3072) v-transpose, 3072 meta, [3073,3329) gather.
// Gather blocks read RAW f32 q/k/v (no dep on other blocks) and rebuild gpos locally
// via the same 1-wave ballot scan as meta (gmask is L2-hot).
__global__ __launch_bounds__(256) void lf_prep1(
    const float* __restrict__ qF, const float* __restrict__ k, const float* __restrict__ v,
    const int* __restrict__ gmask, const int* __restrict__ pmask, const int* __restrict__ nGp,
    u16* __restrict__ kB, u16* __restrict__ vtB,
    int* __restrict__ gpos, unsigned char* __restrict__ gmsk,
    unsigned char* __restrict__ msk, unsigned char* __restrict__ cleanmap,
    u16* __restrict__ gq, u16* __restrict__ gk, u16* __restrict__ gvt, float qscale) {
  const int bid = blockIdx.x;
  const int tid = threadIdx.x;
  if (bid < 2048) {
    int i = (bid * 256 + tid) * 8;
    float4 v0 = *(const float4*)(k + i);
    float4 v1 = *(const float4*)(k + i + 4);
    uint4 w;
    w.x = cvtpk(v0.x, v0.y);
    w.y = cvtpk(v0.z, v0.w);
    w.z = cvtpk(v1.x, v1.y);
    w.w = cvtpk(v1.z, v1.w);
    *(uint4*)(kB + i) = w;
    return;
  }
  if (bid < 3072) {
    __shared__ float t[64][65];
    int b = bid - 2048;
    int h = b >> 6, s0 = (b & 63) << 6;
    int tile = h * 64 + (b & 63);
    int r = tid >> 2, c0 = (tid & 3) << 4;
    const float* src = v + ((size_t)h * SLEN + s0 + r) * DH + c0;
#pragma unroll
    for (int j = 0; j < 16; j += 4) {
      float4 a = *(const float4*)(src + j);
      t[r][c0 + j]     = a.x;
      t[r][c0 + j + 1] = a.y;
      t[r][c0 + j + 2] = a.z;
      t[r][c0 + j + 3] = a.w;
    }
    __syncthreads();
    int d = tid >> 2, j0 = (tid & 3) << 4;
    int grp  = j0 & 32;
    int half = (j0 & 16) ? 4 : 0;
    u16* dst = vtB + ((size_t)tile * 64 + d) * 64 + grp;
#pragma unroll
    for (int q4 = 0; q4 < 4; ++q4) {
      uint2 val;
      val.x = cvtpk(t[j0 + 4 * q4 + 0][d], t[j0 + 4 * q4 + 1][d]);
      val.y = cvtpk(t[j0 + 4 * q4 + 2][d], t[j0 + 4 * q4 + 3][d]);
      *(uint2*)(dst + 8 * q4 + half) = val;
    }
    return;
  }
  if (bid == 3072) {
    // ---- meta block ----
    const int G = imin(nGp[0], GMAX);
    for (int s = tid; s < SLEN; s += 256) {
      unsigned char b = (unsigned char)((pmask[s] ? 1 : 0) | (gmask[s] ? 2 : 0));
      msk[s] = b;
    }
    for (int s = SLEN + tid; s < SLEN + 64; s += 256) msk[s] = 0;
    __syncthreads();
    if (tid < 64) {
      int lane = tid;
      if (lane < GMAX) gmsk[lane] = 0;
      int cnt = 0;
      for (int c = 0; c < SLEN / 64 && cnt < G; ++c) {
        int s = c * 64 + lane;
        bool isg = gmask[s] != 0;
        u64 b = __ballot(isg);
        int rank = cnt + (int)__popcll(b & ((1ull << lane) - 1ull));
        if (isg && rank < G) gpos[rank] = s;
        cnt += (int)__popcll(b);
      }
      if (cnt < G) {
        int fill = cnt;
        for (int c = 0; c < SLEN / 64 && fill < G; ++c) {
          int s = c * 64 + lane;
          bool non = gmask[s] == 0;
          u64 b = __ballot(non);
          int rank = fill + (int)__popcll(b & ((1ull << lane) - 1ull));
          if (non && rank < G) gpos[rank] = s;
          fill += (int)__popcll(b);
        }
      }
    }
    __syncthreads();
    if (tid < 64) {
      if (tid < G) {
        int p = gpos[tid];
        gmsk[tid] = (unsigned char)(pmask[p] ? 1 : 0);
        msk[p] = (unsigned char)(msk[p] | 4);
      }
    } else if (tid >= 128) {
      int c = tid - 128;
      if (c < SLEN / 32) {
        unsigned char ok1 = 1, ok2 = 1;
        for (int kk = 0; kk < 32; ++kk) {
          unsigned char b = msk[c * 32 + kk];
          ok1 &= (unsigned char)(((b & 3) == 1) ? 1 : 0);
          ok2 &= (unsigned char)(b & 1);
        }
        cleanmap[c] = (unsigned char)(ok1 | (ok2 << 1));
      }
    }
    return;
  }
  // ---- gather blocks (3073..3328): rebuild gpos locally, gather from RAW f32 ----
  __shared__ int sGpos[GMAX];
  const int G = imin(nGp[0], GMAX);
  if (tid < 64) {
    int lane = tid;
    int cnt = 0;
    for (int c = 0; c < SLEN / 64 && cnt < G; ++c) {
      int s = c * 64 + lane;
      bool isg = gmask[s] != 0;
      u64 b = __ballot(isg);
      int rank = cnt + (int)__popcll(b & ((1ull << lane) - 1ull));
      if (isg && rank < G) sGpos[rank] = s;
      cnt += (int)__popcll(b);
    }
    if (cnt < G) {
      int fill = cnt;
      for (int c = 0; c < SLEN / 64 && fill < G; ++c) {
        int s = c * 64 + lane;
        bool non = gmask[s] == 0;
        u64 b = __ballot(non);
        int rank = fill + (int)__popcll(b & ((1ull << lane) - 1ull));
        if (non && rank < G) sGpos[rank] = s;
        fill += (int)__popcll(b);
      }
    }
  }
  __syncthreads();
  int idx = (bid - 3073) * 256 + tid;   // 0..65535
  int h = idx >> 12, m = (idx >> 6) & 63, d = idx & 63;
  size_t oq = ((size_t)h * GMAX + m) * DH + d;
  int r = m & 31;
  int pos = ((r & 12) << 1) + ((r & 16) >> 2) + (r & 3);
  size_t ot = ((size_t)h * DH + d) * GMAX + (m & 32) + pos;
  if (m < G) {
    int p = sGpos[m];
    gq[oq]  = f2bf(qF[((size_t)h * SLEN + p) * DH + d] * qscale);
    gk[oq]  = f2bf(k[((size_t)h * SLEN + p) * DH + d]);
    gvt[ot] = f2bf(v[((size_t)h * SLEN + p) * DH + d]);
  } else {
    gq[oq] = 0; gk[oq] = 0; gvt[ot] = 0;
  }
}

// ---------------- unified attention: R13 structure (proven) ----------------
// 1152 blocks x 256 thr. wg XCD-swizzled; wg%9==0 -> global block (128), else local (1024).
// Metadata prestaged in LDS; no global loads in the phase loop except the 4 stage gload_lds.
__global__ __launch_bounds__(256) void lf_attn(
    const float* __restrict__ qF, const u16* __restrict__ kB, const u16* __restrict__ vtB,
    const u16* __restrict__ gkB, const u16* __restrict__ gqB, const u16* __restrict__ gvtB,
    const unsigned char* __restrict__ gmskA, const unsigned char* __restrict__ mskA,
    const unsigned char* __restrict__ cleanA, const int* __restrict__ nGp,
    float* __restrict__ out, float* __restrict__ pAcc, float* __restrict__ pL, float qscale) {
  __shared__ __align__(16) u16 sK[2][4096];
  __shared__ __align__(16) u16 sV[2][4096];
  __shared__ u32 sMsk[192];
  __shared__ u32 sGm[16];

  const int tid  = threadIdx.x;
  const int wv   = tid >> 6;
  const int lane = tid & 63;
  const int ql   = lane & 15;
  const int g    = lane >> 4;
  const float NEGV = -1e30f;
  const float MEXP = 24.0f;
  const int G = imin(nGp[0], GMAX);

  const int wg = ((int)blockIdx.x & 7) * 144 + ((int)blockIdx.x >> 3);
  const bool glob = (wg % 9) == 0;

  int off[4][2];
#pragma unroll
  for (int t = 0; t < 4; ++t)
#pragma unroll
    for (int c = 0; c < 2; ++c) {
      int row = 16 * t + ql;
      off[t][c] = (row * 8 + ((c * 4 + g) ^ (row & 7))) * 8;
    }

  f32x4 acc[4];
#pragma unroll
  for (int i = 0; i < 4; ++i) acc[i] = (f32x4){0.f, 0.f, 0.f, 0.f};
  f32x4 lsv = (f32x4){0.f, 0.f, 0.f, 0.f};
  bf16x8 qf0, qf1;

  int h, s0w = 0, sq = 0, t0, nMain, qg = 0, splitIdx = 0;
  int lo_w = 0, hi_w = 0;
  bool hasG = false;
  const u16 *gks = nullptr, *gvs = nullptr;

  if (!glob) {
    int lid = wg - wg / 9 - 1;           // 0..1023
    h = lid >> 6;
    int qblk = lid & 63;
    int s0 = qblk << 6;
    s0w = s0 + 16 * wv; sq = s0w + ql;
    t0 = imax(0, qblk - 4);
    int t1 = imin(63, qblk + 4);
    nMain = t1 - t0 + 1;
    hasG = (G > 0);
    lo_w = imax(t0, (s0w - WW) >> 6);
    hi_w = imin(t1, (s0w + 15 + WW) >> 6);
    const float* qr = qF + ((size_t)h * SLEN + sq) * DH;
    float4 a0 = *(const float4*)(qr + 8 * g);
    float4 a1 = *(const float4*)(qr + 8 * g + 4);
    float4 b0 = *(const float4*)(qr + 32 + 8 * g);
    float4 b1 = *(const float4*)(qr + 32 + 8 * g + 4);
    union { u32 w[4]; bf16x8 v; } uq;
    uq.w[0] = cvtpk(a0.x * qscale, a0.y * qscale);
    uq.w[1] = cvtpk(a0.z * qscale, a0.w * qscale);
    uq.w[2] = cvtpk(a1.x * qscale, a1.y * qscale);
    uq.w[3] = cvtpk(a1.z * qscale, a1.w * qscale);
    qf0 = uq.v;
    uq.w[0] = cvtpk(b0.x * qscale, b0.y * qscale);
    uq.w[1] = cvtpk(b0.z * qscale, b0.w * qscale);
    uq.w[2] = cvtpk(b1.x * qscale, b1.y * qscale);
    uq.w[3] = cvtpk(b1.z * qscale, b1.w * qscale);
    qf1 = uq.v;
    gks = gkB + (size_t)h * GMAX * DH;
    gvs = gvtB + (size_t)h * 4096;
  } else {
    int gb = wg / 9;                     // 0..127
    h = gb >> 3; splitIdx = gb & 7;
    qg = wv * 16 + ql;
    t0 = splitIdx * 8; nMain = 8;
    const u16* qRow = gqB + ((size_t)h * GMAX + qg) * DH;
    qf0 = *(const bf16x8*)(qRow + 8 * g);
    qf1 = *(const bf16x8*)(qRow + 32 + 8 * g);
  }
  const u16* kbase = kB  + (size_t)h * 64 * 4096;
  const u16* vbase = vtB + (size_t)h * 64 * 4096;
  const int totPh = nMain + (hasG ? 1 : 0);

  const unsigned char cmask = glob ? 2 : 1;
  unsigned char cbyte = 0;
  if (lane < nMain) {
    cbyte = (unsigned char)(cleanA[2 * (t0 + lane)] & cleanA[2 * (t0 + lane) + 1]);
  }
  const u64 cbits = __ballot((cbyte & cmask) != 0);

  auto stage = [&](int p, int b) {
    const u16 *ks, *vs;
    if (hasG && p == 0) { ks = gks; vs = gvs; }
    else {
      int tv = t0 + p - (hasG ? 1 : 0);
      ks = kbase + (size_t)tv * 4096;
      vs = vbase + (size_t)tv * 4096;
    }
#pragma unroll
    for (int j = 0; j < 2; ++j) {
      int gran = (wv * 2 + j) * 64 + lane;
      int sg = gran ^ ((gran >> 3) & 7);
      gload16(ks + (size_t)sg * 8, &sK[b][(wv * 2 + j) * 512]);
      gload16(vs + (size_t)sg * 8, &sV[b][(wv * 2 + j) * 512]);
    }
  };

  auto compute = [&](int p, int buf) {
    const bool isg = (hasG && p == 0);
    const int idx = p - (hasG ? 1 : 0);
    const int tv = t0 + idx;
    const int kb = tv * 64;
    bool doC = glob ? true : (isg || (tv >= lo_w && tv <= hi_w));
    if (!doC) return;
    const u16* sk = &sK[buf][0];
    const u16* sv = &sV[buf][0];
    f32x4 sc[4];
#pragma unroll
    for (int t = 0; t < 4; ++t) sc[t] = (f32x4){0.f, 0.f, 0.f, 0.f};
    __builtin_amdgcn_s_setprio(1);
#pragma unroll
    for (int t = 0; t < 4; ++t) {
      bf16x8 a0 = *(const bf16x8*)(sk + off[t][0]);
      bf16x8 a1 = *(const bf16x8*)(sk + off[t][1]);
      sc[t] = MFMA16(a0, qf0, sc[t]);
      sc[t] = MFMA16(a1, qf1, sc[t]);
    }
    __builtin_amdgcn_s_setprio(0);
    f32x4 pv[4];
    if (isg) {
#pragma unroll
      for (int t = 0; t < 4; ++t) {
        u32 mw = sGm[4 * t + g];
#pragma unroll
        for (int i = 0; i < 4; ++i) {
          float s = ((mw >> (8 * i)) & 1) ? sc[t][i] : NEGV;
          pv[t][i] = __builtin_amdgcn_exp2f(s - MEXP);
        }
      }
    } else {
      bool cl = ((cbits >> idx) & 1) != 0;
      if (!glob) cl = cl && (kb >= s0w + 15 - WW) && (kb + 63 <= s0w + WW);
      if (cl) {
#pragma unroll
        for (int t = 0; t < 4; ++t)
#pragma unroll
          for (int i = 0; i < 4; ++i)
            pv[t][i] = __builtin_amdgcn_exp2f(sc[t][i] - MEXP);
      } else if (glob) {
#pragma unroll
        for (int t = 0; t < 4; ++t) {
          u32 mw = sMsk[(idx << 4) + 4 * t + g];
#pragma unroll
          for (int i = 0; i < 4; ++i) {
            float s = ((mw >> (8 * i)) & 1) ? sc[t][i] : NEGV;
            pv[t][i] = __builtin_amdgcn_exp2f(s - MEXP);
          }
        }
      } else {
#pragma unroll
        for (int t = 0; t < 4; ++t) {
          u32 mw = sMsk[(idx << 4) + 4 * t + g];
#pragma unroll
          for (int i = 0; i < 4; ++i) {
            int kkey = kb + 16 * t + 4 * g + i;
            bool vok = (((mw >> (8 * i)) & 3) == 1) && (kkey >= sq - WW) && (kkey <= sq + WW);
            float s = vok ? sc[t][i] : NEGV;
            pv[t][i] = __builtin_amdgcn_exp2f(s - MEXP);
          }
        }
      }
    }
    lsv += pv[0] + pv[1] + pv[2] + pv[3];
    __builtin_amdgcn_s_setprio(1);
#pragma unroll
    for (int s2 = 0; s2 < 2; ++s2) {
      union { u32 w[4]; bf16x8 v8; } u;
      u.w[0] = cvtpk(pv[2 * s2][0], pv[2 * s2][1]);
      u.w[1] = cvtpk(pv[2 * s2][2], pv[2 * s2][3]);
      u.w[2] = cvtpk(pv[2 * s2 + 1][0], pv[2 * s2 + 1][1]);
      u.w[3] = cvtpk(pv[2 * s2 + 1][2], pv[2 * s2 + 1][3]);
#pragma unroll
      for (int dt = 0; dt < 4; ++dt) {
        bf16x8 vf = *(const bf16x8*)(sv + off[dt][s2]);
        acc[dt] = MFMA16(vf, u.v8, acc[dt]);
      }
    }
    __builtin_amdgcn_s_setprio(0);
  };

  // ---- prologue: stage(0) + metadata into LDS, one full sync ----
  stage(0, 0);
  {
    int nb = nMain << 4;
    if (tid < nb) sMsk[tid] = *(const u32*)(mskA + (t0 << 6) + (tid << 2));
    if (hasG && tid >= 192 && tid < 208) sGm[tid - 192] = *(const u32*)(gmskA + ((tid - 192) << 2));
  }
  __syncthreads();

  // ---- 2-buffer depth-1 pipeline ----
  for (int p = 0; p < totPh; ++p) {
    if (p + 1 < totPh) {
      stage(p + 1, (p + 1) & 1);
      asm volatile("s_waitcnt vmcnt(4)" ::: "memory");
    } else {
      asm volatile("s_waitcnt vmcnt(0)" ::: "memory");
    }
    __builtin_amdgcn_s_barrier();
    __builtin_amdgcn_sched_barrier(0);
    compute(p, p & 1);
    __builtin_amdgcn_s_barrier();
  }

  float lsum = lsv[0] + lsv[1] + lsv[2] + lsv[3];
  lsum += __shfl_xor(lsum, 16);
  lsum += __shfl_xor(lsum, 32);

  if (!glob) {
    float inv = 1.f / lsum;
    bool skip = (mskA[sq] & 4) != 0;
    if (!skip) {
      float* orow = out + ((size_t)h * SLEN + sq) * DH;
#pragma unroll
      for (int dt = 0; dt < 4; ++dt) {
        f32x4 o = acc[dt] * inv;
        *(f32x4*)(orow + dt * 16 + 4 * g) = o;
      }
    }
  } else {
    float* pa = pAcc + ((size_t)(h * 8 + splitIdx) * 64 + qg) * 64;
#pragma unroll
    for (int dt = 0; dt < 4; ++dt)
      *(f32x4*)&pa[dt * 16 + 4 * g] = acc[dt];
    if (g == 0) pL[(h * 8 + splitIdx) * 64 + qg] = lsum;
  }
}

// ---------------- merge the 8 key-splits of global rows ----------------
__global__ void lf_gmerge(const float* __restrict__ pAcc, const float* __restrict__ pL,
                          const int* __restrict__ gpos, const int* __restrict__ nGp,
                          float* __restrict__ out) {
  const int G = imin(nGp[0], GMAX);
  int h = blockIdx.x;
  int tid = threadIdx.x;
#pragma unroll
  for (int it = 0; it < 4; ++it) {
    int v = tid + it * 256;
    int q = v >> 4, d4 = (v & 15) << 2;
    if (q >= G) continue;
    float L = 0.f;
    f32x4 a = (f32x4){0.f, 0.f, 0.f, 0.f};
#pragma unroll
    for (int s = 0; s < 8; ++s) {
      L += pL[(h * 8 + s) * 64 + q];
      a += *(const f32x4*)&pAcc[((size_t)(h * 8 + s) * 64 + q) * 64 + d4];
    }
    *(f32x4*)&out[((size_t)h * SLEN + gpos[q]) * DH + d4] = a * (1.f / L);
  }
}

// ---------------- launch ----------------
extern "C" void kernel_launch(void* const* d_in, const int* in_sizes, int n_in,
                              void* d_out, int out_size, void* d_ws, size_t ws_size,
                              hipStream_t stream) {
  const float* q = (const float*)d_in[0];
  const float* k = (const float*)d_in[1];
  const float* v = (const float*)d_in[2];
  const int* gmask = (const int*)d_in[3];
  const int* pmask = (const int*)d_in[4];
  const int* nGp = (const int*)d_in[5];
  float* out = (float*)d_out;
  char* ws = (char*)d_ws;

  constexpr size_t NEL = (size_t)NH * SLEN * DH;
  constexpr size_t OFF_KBF  = 0;
  constexpr size_t OFF_VTBF = OFF_KBF + NEL * 2;
  constexpr size_t OFF_GK   = OFF_VTBF + NEL * 2 + 256;
  constexpr size_t OFF_GQ   = OFF_GK + (size_t)NH * GMAX * DH * 2;
  constexpr size_t OFF_GVT  = OFF_GQ + (size_t)NH * GMAX * DH * 2;
  constexpr size_t OFF_GPOS = OFF_GVT + (size_t)NH * DH * GMAX * 2;
  constexpr size_t OFF_GMSK = OFF_GPOS + 256;
  constexpr size_t OFF_MSK  = OFF_GMSK + 64;
  constexpr size_t OFF_CLEAN = OFF_MSK + SLEN + 64;
  constexpr size_t OFF_PACC = OFF_CLEAN + 256;
  constexpr size_t OFF_PL   = OFF_PACC + (size_t)NH * 8 * 64 * 64 * 4;

  u16* kB  = (u16*)(ws + OFF_KBF);
  u16* vtB = (u16*)(ws + OFF_VTBF);
  u16* gk  = (u16*)(ws + OFF_GK);
  u16* gq  = (u16*)(ws + OFF_GQ);
  u16* gvt = (u16*)(ws + OFF_GVT);
  int* gpos = (int*)(ws + OFF_GPOS);
  unsigned char* gmsk = (unsigned char*)(ws + OFF_GMSK);
  unsigned char* msk  = (unsigned char*)(ws + OFF_MSK);
  unsigned char* clean = (unsigned char*)(ws + OFF_CLEAN);
  float* pAcc = (float*)(ws + OFF_PACC);
  float* pL   = (float*)(ws + OFF_PL);

  const float qscale = 0.125f * 1.4426950408889634f;  // 1/sqrt(64) * log2(e)

  lf_prep1<<<3329, 256, 0, stream>>>(q, k, v, gmask, pmask, nGp,
                                     kB, vtB, gpos, gmsk, msk, clean,
                                     gq, gk, gvt, qscale);
  lf_attn<<<1152, 256, 0, stream>>>(q, kB, vtB, gk, gq, gvt, gmsk, msk, clean,
                                    nGp, out, pAcc, pL, qscale);
  lf_gmerge<<<NH, 256, 0, stream>>>(pAcc, pL, gpos, nGp, out);
}